// Round 13
// baseline (207.699 us; speedup 1.0000x reference)
//
#include <hip/hip_runtime.h>

#define B_   4
#define T_   2048
#define D_   1024
#define MTOK 8192  // B_*T_

typedef __attribute__((ext_vector_type(8))) _Float16 half8;
typedef __attribute__((ext_vector_type(4))) float    f32x4;

#define GLD(G, L) __builtin_amdgcn_global_load_lds(                       \
    (const __attribute__((address_space(1))) void*)(G),                   \
    (__attribute__((address_space(3))) void*)(L), 16, 0, 0)

#define BAR()   __builtin_amdgcn_s_barrier()
#define BARM()  asm volatile("s_barrier" ::: "memory")
#define LGKM0() do { asm volatile("s_waitcnt lgkmcnt(0)" ::: "memory");   \
                     __builtin_amdgcn_sched_barrier(0); } while (0)
#define VMW(n)  asm volatile("s_waitcnt vmcnt(" #n ")" ::: "memory")

__device__ __forceinline__ unsigned short f2h(float f) {
  return __builtin_bit_cast(unsigned short, (_Float16)f);  // RTE
}
__device__ __forceinline__ float h2f(unsigned short u) {
  return (float)__builtin_bit_cast(_Float16, u);
}

// ---------------- prep: x fp32 -> fp16 (+ zero colsum) --------------
__global__ __launch_bounds__(256) void tofp16_kernel(
    const float4* __restrict__ in, ushort4* __restrict__ out, int n4,
    float4* __restrict__ cs, int c4) {
  int i = blockIdx.x * 256 + threadIdx.x;
  if (i < c4) cs[i] = (float4){0.f, 0.f, 0.f, 0.f};
  if (i >= n4) return;
  float4 v = in[i];
  ushort4 h;
  h.x = f2h(v.x); h.y = f2h(v.y); h.z = f2h(v.z); h.w = f2h(v.w);
  out[i] = h;
}

// ---------------- prep: transpose + concat W -> fp16 ----------------
__global__ __launch_bounds__(256) void wcat_t_kernel(
    const float* __restrict__ Wq, const float* __restrict__ Wk,
    const float* __restrict__ Wv, unsigned short* __restrict__ Wt) {
  __shared__ float tile[32][33];
  int z = blockIdx.z;
  const float* W = (z == 0) ? Wq : ((z == 1) ? Wk : Wv);
  int c0 = blockIdx.x * 32, r0 = blockIdx.y * 32;
  int tx = threadIdx.x & 31, ty = threadIdx.x >> 5;  // 32 x 8
  #pragma unroll
  for (int i = 0; i < 4; ++i)
    tile[ty + i * 8][tx] = W[(size_t)(r0 + ty + i * 8) * D_ + c0 + tx];
  __syncthreads();
  #pragma unroll
  for (int i = 0; i < 4; ++i) {
    float v = tile[tx][ty + i * 8];
    size_t row = (size_t)z * D_ + c0 + ty + i * 8;
    Wt[row * D_ + r0 + tx] = f2h(v);
  }
}

// ---------------- V transpose: QKV cols [2048,3072) -> Vt[b][d][t] --
__global__ __launch_bounds__(256) void vtrans_kernel(
    const unsigned short* __restrict__ QKV, unsigned short* __restrict__ Vt) {
  __shared__ unsigned short tile[64][68];
  int b = blockIdx.z;
  int t0 = blockIdx.x * 64, d0 = blockIdx.y * 64;
  int l16 = threadIdx.x & 15, rr = threadIdx.x >> 4;
  const unsigned short* src =
      QKV + ((size_t)b * 2048 + t0 + rr) * 3072 + 2048 + d0 + l16 * 4;
  #pragma unroll
  for (int i = 0; i < 4; ++i) {
    ushort4 v = *(const ushort4*)(src + (size_t)i * 16 * 3072);
    *(ushort4*)&tile[rr + i * 16][l16 * 4] = v;
  }
  __syncthreads();
  unsigned short* dst = Vt + ((size_t)b * D_ + d0) * 2048 + t0;
  #pragma unroll
  for (int j = 0; j < 4; ++j) {
    int dd = rr + j * 16;
    int tt = l16 * 4;
    ushort4 v;
    v.x = tile[tt + 0][dd]; v.y = tile[tt + 1][dd];
    v.z = tile[tt + 2][dd]; v.w = tile[tt + 3][dd];
    *(ushort4*)(dst + (size_t)dd * 2048 + tt) = v;
  }
}

// ---------------- 8-phase pipelined GEMM, BK=32, FM=4 ---------------
// (QKV engine — unchanged, measured 859 TF at 3 blocks/CU)
template <int EPI>
__global__ __launch_bounds__(512, 4) void gemm8p(
    const unsigned short* __restrict__ A, const unsigned short* __restrict__ B,
    void* __restrict__ C0, float* __restrict__ CS,
    int K, int lda, int ldb, int ldc,
    long aBatch, long bBatch, long cBatch) {
  constexpr int ABY  = 128 * 64;        // 8192 B
  constexpr int BUFB = ABY + 16384;     // 24576 B
  __shared__ __align__(16) char lds[2 * BUFB];

  const int z = blockIdx.z;
  A += (size_t)z * aBatch;
  B += (size_t)z * bBatch;

  const int nwg = gridDim.x * gridDim.y;
  int s = blockIdx.y * gridDim.x + blockIdx.x;
  s = (s & 7) * (nwg >> 3) + (s >> 3);
  const int bx = s % gridDim.x, by = s / gridDim.x;
  const int brow = by * 128, bcol = bx * 256;

  const int tid = threadIdx.x;
  const int wid = tid >> 6, lane = tid & 63;
  const int wr = wid >> 2, wc = wid & 3;
  const int l15 = lane & 15, g4 = lane >> 4;

  const int scol = ((lane & 3) ^ ((lane >> 3) & 3)) * 8;
  const int srow = lane >> 2;
  int aoff, adst, boffs[2], bdst[2];
  {
    int r0 = wid * 16;  // whole A staged as one unit (phase 4 only)
    aoff = (brow + r0 + srow) * lda + scol;
    adst = r0 * 64;
    #pragma unroll
    for (int rg = 0; rg < 2; ++rg) {
      int rb = (wid >> 1) * 64 + rg * 32 + (wid & 1) * 16;  // B-nh{rg} union
      boffs[rg] = (bcol + rb + srow) * ldb + scol;
      bdst[rg]  = ABY + rb * 64;
    }
  }

  const int rslot = (g4 ^ ((l15 >> 1) & 3)) * 16;
  int aRd[2], bRd[2];
  #pragma unroll
  for (int mh = 0; mh < 2; ++mh) {
    aRd[mh] = (wr * 64 + mh * 32 + l15) * 64 + rslot;
    bRd[mh] = ABY + (wc * 64 + mh * 32 + l15) * 64 + rslot;
  }

#define STAGE_A(bb, tt) \
    GLD(A + (size_t)(aoff + (tt) * 32), lds + (bb) * BUFB + adst)
#define STAGE_B(nh, bb, tt) \
    GLD(B + (size_t)(boffs[nh] + (tt) * 32), lds + (bb) * BUFB + bdst[nh])
#define LOAD_A(mh) do { _Pragma("unroll")                                     \
    for (int mf = 0; mf < 2; ++mf)                                            \
      ar[mf] = *(const half8*)(buf + aRd[mh] + mf * 1024); } while (0)
#define LOAD_B(dst, nh) do { _Pragma("unroll")                                \
    for (int nf = 0; nf < 2; ++nf)                                            \
      dst[nf] = *(const half8*)(buf + bRd[nh] + nf * 1024); } while (0)
#define MFMA_Q(mh, nh, br) do { _Pragma("unroll")                             \
    for (int mf = 0; mf < 2; ++mf) { _Pragma("unroll")                        \
      for (int nf = 0; nf < 2; ++nf) {                                        \
        f32x4& ac = acc[(mh) * 2 + mf][(nh) * 2 + nf];                        \
        ac = __builtin_amdgcn_mfma_f32_16x16x32_f16(ar[mf], br[nf], ac, 0, 0, 0); \
      } } } while (0)

  // prologue: stage K-tiles 0 and 1
  STAGE_A(0, 0); STAGE_B(0, 0, 0); STAGE_B(1, 0, 0);
  STAGE_A(1, 1); STAGE_B(0, 1, 1); STAGE_B(1, 1, 1);
  VMW(3);  // buf0 complete
  BAR();

  f32x4 acc[4][4] = {};
  half8 ar[2], b0r[2], b1r[2];
  const int nIter = K / 64;

  for (int it = 0; it < nIter; ++it) {
    const bool st = (it + 1 < nIter);
    #pragma unroll
    for (int h = 0; h < 2; ++h) {
      const char* buf = lds + h * BUFB;
      const int tt = 2 * it + 2 + h;
      LOAD_A(0); LOAD_B(b0r, 0);
      BAR(); LGKM0();
      __builtin_amdgcn_s_setprio(1); MFMA_Q(0, 0, b0r);
      __builtin_amdgcn_s_setprio(0); BAR();
      LOAD_B(b1r, 1);
      if (st) STAGE_B(0, h, tt);
      BAR(); LGKM0();
      __builtin_amdgcn_s_setprio(1); MFMA_Q(0, 1, b1r);
      __builtin_amdgcn_s_setprio(0); BAR();
      LOAD_A(1);
      if (st) STAGE_B(1, h, tt);
      BAR(); LGKM0();
      __builtin_amdgcn_s_setprio(1); MFMA_Q(1, 1, b1r);
      __builtin_amdgcn_s_setprio(0); BAR();
      if (st) STAGE_A(h, tt);
      BAR();
      __builtin_amdgcn_s_setprio(1); MFMA_Q(1, 0, b0r);
      __builtin_amdgcn_s_setprio(0);
      if (st) { VMW(3); } else { VMW(0); }
      BAR();
    }
  }

  // epilogue (EPI==1: fp16 row-major store)
  unsigned short* C = (unsigned short*)C0 + (size_t)z * cBatch;
  #pragma unroll
  for (int m = 0; m < 4; ++m) {
    int rowoff = (m >> 1) * 32 + (m & 1) * 16;
    #pragma unroll
    for (int n = 0; n < 4; ++n) {
      int coloff = (n >> 1) * 32 + (n & 1) * 16;
      #pragma unroll
      for (int r = 0; r < 4; ++r) {
        int row = brow + wr * 64 + rowoff + g4 * 4 + r;
        int col = bcol + wc * 64 + coloff + l15;
        C[(size_t)row * ldc + col] = f2h(acc[m][n][r]);
      }
    }
  }
#undef STAGE_A
#undef STAGE_B
#undef LOAD_A
#undef LOAD_B
#undef MFMA_Q
}

// ---------------- scores GEMM: 128x128, 4 waves, 3-buf 1-bar --------
// C = A*B^T (bt-form), fp16 store + fused colsum of exp(s-64).
// 256 thr = 4 waves (2x2), 64x64 panels (8 reads / 16 MFMA).  LDS
// 3 x 16 KB = 48 KB -> 3 blocks/CU.  Grid (16,16,4) = 1024 blocks.
// 3-buffer rotation: stage buf[t+2] whole (4 GLD/wave), read buf[t];
// tile-top barrier orders write-after-read.  vmcnt: steady VMW(4).
__global__ __launch_bounds__(256, 3) void gemmS(
    const unsigned short* __restrict__ A, const unsigned short* __restrict__ B,
    unsigned short* __restrict__ C0, float* __restrict__ CS,
    int K, int lda, int ldb, int ldc,
    long aBatch, long bBatch, long cBatch) {
  constexpr int ABY  = 128 * 64;      // 8192 B
  constexpr int BUFB = ABY + 8192;    // 16384 B
  __shared__ __align__(16) char lds[3 * BUFB];

  const int z = blockIdx.z;
  A += (size_t)z * aBatch;
  B += (size_t)z * bBatch;

  const int nwg = gridDim.x * gridDim.y;  // 256
  int s = blockIdx.y * gridDim.x + blockIdx.x;
  s = (s & 7) * (nwg >> 3) + (s >> 3);
  const int bx = s % gridDim.x, by = s / gridDim.x;
  const int brow = by * 128, bcol = bx * 128;

  const int tid = threadIdx.x;
  const int wid = tid >> 6, lane = tid & 63;
  const int wr = wid >> 1, wc = wid & 1;
  const int l15 = lane & 15, g4 = lane >> 4;

  // staging: wave wid stages A rows [wid*32, wid*32+32) and B same (2 lines each)
  const int scol = ((lane & 3) ^ ((lane >> 3) & 3)) * 8;
  const int srow = lane >> 2;
  int aoffs[2], adst[2], boffs[2], bdst[2];
  #pragma unroll
  for (int g = 0; g < 2; ++g) {
    int r0 = wid * 32 + g * 16;
    aoffs[g] = (brow + r0 + srow) * lda + scol;
    adst[g]  = r0 * 64;
    boffs[g] = (bcol + r0 + srow) * ldb + scol;
    bdst[g]  = ABY + r0 * 64;
  }

  const int rslot = (g4 ^ ((l15 >> 1) & 3)) * 16;
  int aRd[4], bRd[4];
  #pragma unroll
  for (int mf = 0; mf < 4; ++mf)
    aRd[mf] = (wr * 64 + mf * 16 + l15) * 64 + rslot;
  #pragma unroll
  for (int nf = 0; nf < 4; ++nf)
    bRd[nf] = ABY + (wc * 64 + nf * 16 + l15) * 64 + rslot;

#define S_STAGE(base, tt) do { _Pragma("unroll")                              \
    for (int g = 0; g < 2; ++g) {                                             \
      GLD(A + (size_t)(aoffs[g] + (tt) * 32), (base) + adst[g]);              \
      GLD(B + (size_t)(boffs[g] + (tt) * 32), (base) + bdst[g]); } } while (0)

  char* bufA = lds;
  char* bufB = lds + BUFB;
  char* bufC = lds + 2 * BUFB;

  S_STAGE(bufA, 0);
  S_STAGE(bufB, 1);
  VMW(4);  // buf0 complete; buf1's 4 may remain in flight

  f32x4 acc[4][4] = {};
  half8 ar[4], br[4];
  const int NT = K / 32;  // 32

  for (int t = 0; t < NT; ++t) {
    BARM();
    const bool st = (t + 2 < NT);
    if (st) S_STAGE(bufC, t + 2);
    #pragma unroll
    for (int mf = 0; mf < 4; ++mf)
      ar[mf] = *(const half8*)(bufA + aRd[mf]);
    #pragma unroll
    for (int nf = 0; nf < 4; ++nf)
      br[nf] = *(const half8*)(bufA + bRd[nf]);
    __builtin_amdgcn_s_setprio(1);
    #pragma unroll
    for (int mf = 0; mf < 4; ++mf)
      #pragma unroll
      for (int nf = 0; nf < 4; ++nf)
        acc[mf][nf] = __builtin_amdgcn_mfma_f32_16x16x32_f16(ar[mf], br[nf], acc[mf][nf], 0, 0, 0);
    __builtin_amdgcn_s_setprio(0);
    if (st)                VMW(4);
    else if (t + 2 == NT)  VMW(0);
    char* tmp = bufA; bufA = bufB; bufB = bufC; bufC = tmp;
  }

  // epilogue: fp16 store + fused colsum of exp(s-64)
  unsigned short* C = C0 + (size_t)z * cBatch;
  float csum[4] = {0.f, 0.f, 0.f, 0.f};
  #pragma unroll
  for (int mf = 0; mf < 4; ++mf)
    #pragma unroll
    for (int nf = 0; nf < 4; ++nf)
      #pragma unroll
      for (int r = 0; r < 4; ++r) {
        int row = brow + wr * 64 + mf * 16 + g4 * 4 + r;
        int col = bcol + wc * 64 + nf * 16 + l15;
        unsigned short hh = f2h(acc[mf][nf][r]);
        C[(size_t)row * ldc + col] = hh;
        csum[nf] += __expf(h2f(hh) - 64.0f);
      }
  #pragma unroll
  for (int nf = 0; nf < 4; ++nf) {
    csum[nf] += __shfl_xor(csum[nf], 16);
    csum[nf] += __shfl_xor(csum[nf], 32);
  }
  if (g4 == 0) {
    #pragma unroll
    for (int nf = 0; nf < 4; ++nf) {
      int col = bcol + wc * 64 + nf * 16 + l15;
      unsafeAtomicAdd(CS + (size_t)z * T_ + col, csum[nf]);
    }
  }
#undef S_STAGE
}

// ---------------- PV GEMM: BM=64/BN=256, A prefetched 1 tile deep ---
// out[q][d] = sum_k w[q][k]*Vt[d][k], w = exp(s-64)*u[k].  4 waves,
// 64x64 panels.  Grid (4,32,4)=512 = 2 blocks/CU.  3 LDS buffers.
// KEY FIX (r13): A-loads (Sc + u) are issued ONE TILE EARLY into
// ping-pong register sets (unroll-2, static names) — full-tile latency
// cover for the L2-missing Sc reads that stalled r8-r12 every tile.
// Ledger (7 issues/tile: 4 B-GLD + 3 A-loads): steady VMW(7); tails
// VMW(4) at t=NT-3, VMW(0) at t=NT-2.
__global__ __launch_bounds__(256, 2) void gemmPV(
    const unsigned short* __restrict__ Sc, const float* __restrict__ U,
    const unsigned short* __restrict__ Bv, float* __restrict__ out) {
  constexpr int ABY  = 64 * 64;       // 4096 B
  constexpr int BUFB = ABY + 16384;   // 20480 B
  __shared__ __align__(16) char lds[3 * BUFB];

  const int b = blockIdx.z;
  Sc += (size_t)b * T_ * T_;
  U  += (size_t)b * T_;
  Bv += (size_t)b * D_ * T_;
  float* Co = out + (size_t)b * T_ * D_;

  const int nwg = gridDim.x * gridDim.y;  // 128
  int s = blockIdx.y * gridDim.x + blockIdx.x;
  s = (s & 7) * (nwg >> 3) + (s >> 3);
  const int bx = s % gridDim.x, by = s / gridDim.x;
  const int brow = by * 64, bcol = bx * 256;

  const int tid = threadIdx.x;
  const int wid = tid >> 6, lane = tid & 63;
  const int l15 = lane & 15, g4 = lane >> 4;

  const int arow = tid >> 2;
  const unsigned short* aSrc = Sc + (size_t)(brow + arow) * T_ + (tid & 3) * 8;
  const int awB  = arow * 64 + ((tid & 3) ^ ((tid >> 3) & 3)) * 16;
  const int ucol = (tid & 3) * 8;

  const int scol = ((lane & 3) ^ ((lane >> 3) & 3)) * 8;
  const int srow = lane >> 2;
  int boffs[4], bdst[4];
  #pragma unroll
  for (int g = 0; g < 4; ++g) {
    int rb = g * 64 + wid * 16;
    boffs[g] = (bcol + rb + srow) * T_ + scol;
    bdst[g]  = ABY + rb * 64;
  }

  const int rslot = (g4 ^ ((l15 >> 1) & 3)) * 16;
  int aRd[4], bRd[4];
  #pragma unroll
  for (int mf = 0; mf < 4; ++mf)
    aRd[mf] = (mf * 16 + l15) * 64 + rslot;
  #pragma unroll
  for (int nf = 0; nf < 4; ++nf)
    bRd[nf] = ABY + (wid * 64 + nf * 16 + l15) * 64 + rslot;

#define PV_BSTAGE(base, tt) do { _Pragma("unroll")                            \
    for (int g = 0; g < 4; ++g)                                               \
      GLD(Bv + (size_t)(boffs[g] + (tt) * 32), (base) + bdst[g]); } while (0)
#define PV_ALOAD(rA, uA, uB, tt) do {                                         \
    rA = *(const uint4*)(aSrc + (size_t)(tt) * 32);                           \
    uA = *(const float4*)(U + (tt) * 32 + ucol);                              \
    uB = *(const float4*)(U + (tt) * 32 + ucol + 4); } while (0)
#define PV_AWRITE(base, rA, uA, uB) do {                                      \
    const unsigned short* hp = (const unsigned short*)&rA;                    \
    float uu[8] = {uA.x, uA.y, uA.z, uA.w, uB.x, uB.y, uB.z, uB.w};           \
    unsigned int w_[4];                                                       \
    _Pragma("unroll") for (int j = 0; j < 4; ++j) {                           \
      float w0 = __expf(h2f(hp[2 * j])     - 64.f) * uu[2 * j];               \
      float w1 = __expf(h2f(hp[2 * j + 1]) - 64.f) * uu[2 * j + 1];           \
      w_[j] = (unsigned int)f2h(w0) | ((unsigned int)f2h(w1) << 16); }        \
    *(uint4*)((base) + awB) = *(uint4*)w_; } while (0)
#define PV_COMPUTE() do {                                                     \
    _Pragma("unroll") for (int mf = 0; mf < 4; ++mf)                          \
      ar[mf] = *(const half8*)(bufA + aRd[mf]);                               \
    _Pragma("unroll") for (int nf = 0; nf < 4; ++nf)                          \
      br[nf] = *(const half8*)(bufA + bRd[nf]);                               \
    __builtin_amdgcn_s_setprio(1);                                            \
    _Pragma("unroll") for (int mf = 0; mf < 4; ++mf)                          \
      _Pragma("unroll") for (int nf = 0; nf < 4; ++nf)                        \
        acc[mf][nf] = __builtin_amdgcn_mfma_f32_16x16x32_f16(                 \
            ar[mf], br[nf], acc[mf][nf], 0, 0, 0);                            \
    __builtin_amdgcn_s_setprio(0); } while (0)
// One tile: consume CUR set (A(t+2), issued at t-1), issue NXT (A(t+3)).
#define PV_TILE(t, rC, uCa, uCb, rN, uNa, uNb) do {                           \
    BARM();                                                                   \
    if ((t) + 2 < NT) PV_BSTAGE(bufC, (t) + 2);                               \
    if ((t) + 3 < NT) PV_ALOAD(rN, uNa, uNb, (t) + 3);                        \
    PV_COMPUTE();                                                             \
    if ((t) + 3 < NT)      VMW(7);                                            \
    else if ((t) + 2 < NT) VMW(4);                                            \
    else if ((t) + 2 == NT) VMW(0);                                           \
    if ((t) + 2 < NT) {                                                       \
      PV_AWRITE(bufC, rC, uCa, uCb);                                          \
      asm volatile("s_waitcnt lgkmcnt(0)" ::: "memory");                      \
    }                                                                         \
    { char* tmp = bufA; bufA = bufB; bufB = bufC; bufC = tmp; } } while (0)

  char* bufA = lds;
  char* bufB = lds + BUFB;
  char* bufC = lds + 2 * BUFB;

  uint4 rA_E, rA_O; float4 uAa_E, uAb_E, uAa_O, uAb_O;

  // ---- prologue: tiles 0,1 direct; A(2) into O-set ----
  uint4 rA0; float4 uA0a, uA0b;
  PV_ALOAD(rA0, uA0a, uA0b, 0);          // 3
  PV_BSTAGE(bufA, 0);                    // +4 = 7
  uint4 rA1; float4 uA1a, uA1b;
  PV_ALOAD(rA1, uA1a, uA1b, 1);          // +3 = 10
  PV_BSTAGE(bufB, 1);                    // +4 = 14
  PV_ALOAD(rA_O, uAa_O, uAb_O, 2);       // +3 = 17
  VMW(14);                               // A(0) done
  PV_AWRITE(bufA, rA0, uA0a, uA0b);
  VMW(7);                                // B(0)+A(1) done; leaves B(1)+A(2)
  PV_AWRITE(bufB, rA1, uA1a, uA1b);
  asm volatile("s_waitcnt lgkmcnt(0)" ::: "memory");

  f32x4 acc[4][4] = {};
  half8 ar[4], br[4];
  const int NT = T_ / 32;  // 64 (even)

  for (int t = 0; t < NT; t += 2) {
    PV_TILE(t,     rA_O, uAa_O, uAb_O, rA_E, uAa_E, uAb_E);  // even: consume O
    PV_TILE(t + 1, rA_E, uAa_E, uAb_E, rA_O, uAa_O, uAb_O);  // odd : consume E
  }

  // epilogue: coalesced fp32 stores
  #pragma unroll
  for (int mf = 0; mf < 4; ++mf)
    #pragma unroll
    for (int nf = 0; nf < 4; ++nf)
      #pragma unroll
      for (int r = 0; r < 4; ++r) {
        int row = brow + mf * 16 + g4 * 4 + r;
        int col = bcol + wid * 64 + nf * 16 + l15;
        Co[(size_t)row * D_ + col] = acc[mf][nf][r];
      }
#undef PV_BSTAGE
#undef PV_ALOAD
#undef PV_AWRITE
#undef PV_COMPUTE
#undef PV_TILE
}

// ------- invert column sums ----------------------------------------
__global__ __launch_bounds__(256) void sm_stats(const float* __restrict__ cs,
                                                float* __restrict__ stats) {
  int i = blockIdx.x * 256 + threadIdx.x;  // b*2048 + k
  stats[i] = 1.0f / cs[i];
}

// --------------------------------------------------------------------
extern "C" void kernel_launch(void* const* d_in, const int* in_sizes, int n_in,
                              void* d_out, int out_size, void* d_ws, size_t ws_size,
                              hipStream_t stream) {
  const float* x  = (const float*)d_in[0];
  const float* Wq = (const float*)d_in[1];
  const float* Wk = (const float*)d_in[2];
  const float* Wv = (const float*)d_in[3];
  float* out = (float*)d_out;

  char* ws = (char*)d_ws;
  const size_t MB = 1024ull * 1024ull;
  unsigned short* scoresh = (unsigned short*)(ws);             // 32 MB fp16
  unsigned short* QKVh = (unsigned short*)(ws + 32 * MB);      // 48 MB [8192][3072]
  unsigned short* Vt   = (unsigned short*)(ws + 80 * MB);      // 16 MB [4][1024][2048]
  unsigned short* xh   = (unsigned short*)(ws + 96 * MB);      // 16 MB fp16 x
  unsigned short* Wt   = (unsigned short*)(ws + 112 * MB);     // 6 MB  [3072][1024]
  float* colsum = (float*)(ws + 118 * MB);                     // 32 KB [4][2048]
  float* stats  = (float*)(ws + 118 * MB + 64 * 1024);         // 32 KB fp32 u

  // 1. x -> fp16 (+ zero colsum)
  tofp16_kernel<<<MTOK * D_ / 4 / 256, 256, 0, stream>>>(
      (const float4*)x, (ushort4*)xh, MTOK * D_ / 4,
      (float4*)colsum, B_ * T_ / 4);

  // 2. transpose + concat W -> fp16
  wcat_t_kernel<<<dim3(32, 32, 3), 256, 0, stream>>>(Wq, Wk, Wv, Wt);

  // 3. fused QKV projection (768 blocks -> 3 blocks/CU, 859 TF)
  gemm8p<1><<<dim3(3072 / 256, MTOK / 128, 1), 512, 0, stream>>>(
      xh, Wt, QKVh, nullptr, D_, D_, D_, 3072, 0, 0, 0);

  // 4. V transpose -> Vt[b][d][t]
  vtrans_kernel<<<dim3(T_ / 64, D_ / 64, B_), 256, 0, stream>>>(QKVh, Vt);

  // 5. scores = Q K^T, fp16 + fused colsum (1024 blocks -> 3/CU)
  gemmS<<<dim3(T_ / 128, T_ / 128, B_), 256, 0, stream>>>(
      QKVh, QKVh + 1024, scoresh, colsum, D_, 3072, 3072, T_,
      (long)T_ * 3072, (long)T_ * 3072, (long)T_ * T_);

  // 6. u = 1/colsum
  sm_stats<<<B_ * T_ / 256, 256, 0, stream>>>(colsum, stats);

  // 7. out = exp(S-64)*u @ V  (A-prefetched pipeline)
  gemmPV<<<dim3(D_ / 256, T_ / 64, B_), 256, 0, stream>>>(
      scoresh, stats, Vt, out);
}